// Round 7
// baseline (951.108 us; speedup 1.0000x reference)
//
#include <hip/hip_runtime.h>

#define Bn 64
#define Sn 512
#define EB 768
#define Hn 64
#define G3 192
#define Tn 16
#define Pn 32

__device__ __forceinline__ float sigmoidf_(float x) { return 1.f / (1.f + __expf(-x)); }
__device__ __forceinline__ float tanhf_(float x) { return 1.f - 2.f / (__expf(2.f * x) + 1.f); }

__device__ __forceinline__ unsigned short f2bf(float x) {
  union { float f; unsigned u; } v; v.f = x;
  unsigned r = v.u + 0x7fff + ((v.u >> 16) & 1);  // RNE
  return (unsigned short)(r >> 16);
}

typedef __attribute__((ext_vector_type(8))) short short8;
typedef __attribute__((ext_vector_type(4))) float f32x4;

// ---------------- K1: C(32768x384) = bert(32768x768) @ [Wf;Wb]^T + bias, bf16 MFMA
__global__ __launch_bounds__(256) void gemm_mfma(const float* __restrict__ A,
                                                 const float* __restrict__ Wf,
                                                 const float* __restrict__ Wb,
                                                 const float* __restrict__ bf,
                                                 const float* __restrict__ bb,
                                                 float* __restrict__ C) {
  __shared__ __align__(16) unsigned short As[128 * 40];
  __shared__ __align__(16) unsigned short Bs[128 * 40];
  const int tid = threadIdx.x;
  const int n0 = blockIdx.x * 128;
  const int m0 = blockIdx.y * 128;
  const int wv = tid >> 6;
  const int lane = tid & 63;
  const int wm = (wv >> 1) * 64, wn = (wv & 1) * 64;
  const int fr = lane & 15, fq = lane >> 4;
  const int srow = tid >> 1;
  const int shalf = (tid & 1) * 16;
  const int bcol = n0 + srow;
  const float* Wrow = (bcol < G3) ? (Wf + (size_t)bcol * EB) : (Wb + (size_t)(bcol - G3) * EB);
  const float* Arow = A + (size_t)(m0 + srow) * EB;
  f32x4 acc[4][4];
#pragma unroll
  for (int i = 0; i < 4; ++i)
#pragma unroll
    for (int j = 0; j < 4; ++j) acc[i][j] = (f32x4){0.f, 0.f, 0.f, 0.f};

  for (int k0 = 0; k0 < EB; k0 += 32) {
    float4 a0 = *(const float4*)&Arow[k0 + shalf + 0];
    float4 a1 = *(const float4*)&Arow[k0 + shalf + 4];
    float4 a2 = *(const float4*)&Arow[k0 + shalf + 8];
    float4 a3 = *(const float4*)&Arow[k0 + shalf + 12];
    float4 b0 = *(const float4*)&Wrow[k0 + shalf + 0];
    float4 b1 = *(const float4*)&Wrow[k0 + shalf + 4];
    float4 b2 = *(const float4*)&Wrow[k0 + shalf + 8];
    float4 b3 = *(const float4*)&Wrow[k0 + shalf + 12];
    __syncthreads();
    short8 pa, pb;
    pa[0] = f2bf(a0.x); pa[1] = f2bf(a0.y); pa[2] = f2bf(a0.z); pa[3] = f2bf(a0.w);
    pa[4] = f2bf(a1.x); pa[5] = f2bf(a1.y); pa[6] = f2bf(a1.z); pa[7] = f2bf(a1.w);
    *(short8*)&As[srow * 40 + shalf] = pa;
    pa[0] = f2bf(a2.x); pa[1] = f2bf(a2.y); pa[2] = f2bf(a2.z); pa[3] = f2bf(a2.w);
    pa[4] = f2bf(a3.x); pa[5] = f2bf(a3.y); pa[6] = f2bf(a3.z); pa[7] = f2bf(a3.w);
    *(short8*)&As[srow * 40 + shalf + 8] = pa;
    pb[0] = f2bf(b0.x); pb[1] = f2bf(b0.y); pb[2] = f2bf(b0.z); pb[3] = f2bf(b0.w);
    pb[4] = f2bf(b1.x); pb[5] = f2bf(b1.y); pb[6] = f2bf(b1.z); pb[7] = f2bf(b1.w);
    *(short8*)&Bs[srow * 40 + shalf] = pb;
    pb[0] = f2bf(b2.x); pb[1] = f2bf(b2.y); pb[2] = f2bf(b2.z); pb[3] = f2bf(b2.w);
    pb[4] = f2bf(b3.x); pb[5] = f2bf(b3.y); pb[6] = f2bf(b3.z); pb[7] = f2bf(b3.w);
    *(short8*)&Bs[srow * 40 + shalf + 8] = pb;
    __syncthreads();
    short8 af[4], bfv[4];
#pragma unroll
    for (int i = 0; i < 4; ++i) af[i] = *(short8*)&As[(wm + i * 16 + fr) * 40 + fq * 8];
#pragma unroll
    for (int j = 0; j < 4; ++j) bfv[j] = *(short8*)&Bs[(wn + j * 16 + fr) * 40 + fq * 8];
#pragma unroll
    for (int i = 0; i < 4; ++i)
#pragma unroll
      for (int j = 0; j < 4; ++j)
        acc[i][j] = __builtin_amdgcn_mfma_f32_16x16x32_bf16(af[i], bfv[j], acc[i][j], 0, 0, 0);
  }
#pragma unroll
  for (int j = 0; j < 4; ++j) {
    int col = n0 + wn + j * 16 + fr;
    float bias = (col < G3) ? bf[col] : bb[col - G3];
#pragma unroll
    for (int i = 0; i < 4; ++i) {
      int rowb = m0 + wm + i * 16 + fq * 4;
#pragma unroll
      for (int rg = 0; rg < 4; ++rg)
        C[(size_t)(rowb + rg) * 384 + col] = acc[i][j][rg] + bias;
    }
  }
}

// ---------------- K2: Bi-GRU, ONE wave per (b,dir), weights in VGPRs ---------
// Lane l owns row l; all 192 Whh weights for rows {l,64+l,128+l} pinned in
// VGPRs. Single wave => DS program order replaces barriers entirely. Per step:
// 1 ds_write(h) + 16 broadcast ds_read_b128 + 192 FMA + activation + 1 store.
__global__ __launch_bounds__(64, 1) void gru_kernel(const float* __restrict__ C,
                                                    const float* __restrict__ Whh_f,
                                                    const float* __restrict__ bhh_f,
                                                    const float* __restrict__ Whh_b,
                                                    const float* __restrict__ bhh_b,
                                                    float* __restrict__ out) {
  __shared__ __align__(16) float hbuf[64];
  const int wg = blockIdx.x;
  const int rev = (wg >= Bn) ? 1 : 0;
  const int b = wg & (Bn - 1);
  const int l = threadIdx.x;
  const float* Whh = rev ? Whh_b : Whh_f;
  const float* bhh = rev ? bhh_b : bhh_f;
  const int colBase = rev ? G3 : 0;
  const int dirOff = rev ? Hn : 0;
  float4 wv[3][16];
#pragma unroll
  for (int g = 0; g < 3; ++g)
#pragma unroll
    for (int q = 0; q < 16; ++q) {
      wv[g][q] = *(const float4*)&Whh[(size_t)(g * 64 + l) * 64 + 4 * q];
      asm volatile("" : "+v"(wv[g][q].x), "+v"(wv[g][q].y), "+v"(wv[g][q].z), "+v"(wv[g][q].w));
    }
  const float brr = bhh[l], bzz = bhh[64 + l], bnn = bhh[128 + l];
  hbuf[l] = 0.f;
  float h = 0.f;
  int tt = rev ? (Sn - 1) : 0;
  const int stp = rev ? -1 : 1;
  const float* x0 = C + (size_t)(b * Sn + tt) * 384 + colBase;
  float xr = x0[l], xz = x0[64 + l], xn = x0[128 + l];
  for (int t = 0; t < Sn; ++t) {
    // prefetch next x (global loads in flight across the whole step; no
    // barrier exists to force a vmcnt drain)
    float nxr = 0.f, nxz = 0.f, nxn = 0.f;
    if (t + 1 < Sn) {
      const float* xq = C + (size_t)(b * Sn + tt + stp) * 384 + colBase;
      nxr = xq[l]; nxz = xq[64 + l]; nxn = xq[128 + l];
    }
    float4 ar4 = {0.f, 0.f, 0.f, 0.f};
    float4 az4 = {0.f, 0.f, 0.f, 0.f};
    float4 an4 = {0.f, 0.f, 0.f, 0.f};
#pragma unroll
    for (int q = 0; q < 16; ++q) {
      float4 hq = *(const float4*)&hbuf[q * 4];  // broadcast, conflict-free
      ar4.x += wv[0][q].x * hq.x; ar4.y += wv[0][q].y * hq.y;
      ar4.z += wv[0][q].z * hq.z; ar4.w += wv[0][q].w * hq.w;
      az4.x += wv[1][q].x * hq.x; az4.y += wv[1][q].y * hq.y;
      az4.z += wv[1][q].z * hq.z; az4.w += wv[1][q].w * hq.w;
      an4.x += wv[2][q].x * hq.x; an4.y += wv[2][q].y * hq.y;
      an4.z += wv[2][q].z * hq.z; an4.w += wv[2][q].w * hq.w;
    }
    float dr = (ar4.x + ar4.y) + (ar4.z + ar4.w);
    float dz = (az4.x + az4.y) + (az4.z + az4.w);
    float dn = (an4.x + an4.y) + (an4.z + an4.w);
    float rg = sigmoidf_(xr + brr + dr);
    float zg = sigmoidf_(xz + bzz + dz);
    float ng = tanhf_(xn + rg * (bnn + dn));
    h = (1.f - zg) * ng + zg * h;
    hbuf[l] = h;  // program order within the single wave: next iter's reads see it
    out[(size_t)(b * Sn + tt) * (2 * Hn) + dirOff + l] = h;
    tt += stp;
    xr = nxr; xz = nxz; xn = nxn;
  }
}

// ---------------- K3: qkv projection -----------------------------------------
__global__ __launch_bounds__(256) void qkv_kernel(const float* __restrict__ in2,
                                                  const float* __restrict__ Wqkv,
                                                  const float* __restrict__ bqkv,
                                                  float* __restrict__ qb,
                                                  float* __restrict__ kb,
                                                  float* __restrict__ vb) {
  __shared__ float Ws[96 * 32];
  __shared__ float bs[96];
  const int tid = threadIdx.x;
  for (int i = tid; i < 96 * 32; i += 256) Ws[i] = Wqkv[i];
  if (tid < 96) bs[tid] = bqkv[tid];
  __syncthreads();
  const int idx = blockIdx.x * 256 + tid;
  float x[32];
#pragma unroll
  for (int d4 = 0; d4 < 8; ++d4) {
    float4 v = *(const float4*)&in2[(size_t)idx * 32 + d4 * 4];
    x[d4 * 4 + 0] = v.x; x[d4 * 4 + 1] = v.y; x[d4 * 4 + 2] = v.z; x[d4 * 4 + 3] = v.w;
  }
  for (int g = 0; g < 96; ++g) {
    float a = bs[g];
#pragma unroll
    for (int d = 0; d < 32; ++d) a += x[d] * Ws[g * 32 + d];
    float* dst = (g < 32) ? qb : ((g < 64) ? kb : vb);
    dst[(size_t)idx * 32 + (g & 31)] = a;
  }
}

// ---------------- K4a: attention split-K partial (flash-style) ----------------
__global__ __launch_bounds__(256) void attn_split(const float* __restrict__ qb,
                                                  const float* __restrict__ kb,
                                                  const float* __restrict__ vb,
                                                  float* __restrict__ part) {
  __shared__ __align__(16) float Ks[128 * 32];
  __shared__ __align__(16) float Vs[128 * 32];
  const int tid = threadIdx.x;
  const int blk = blockIdx.x;
  const int b = blk >> 3;
  const int qhalf = (blk >> 2) & 1;
  const int split = blk & 3;
  const int k0 = split * 128;
#pragma unroll
  for (int i = 0; i < 4; ++i) {
    int f = tid + 256 * i;
    int row = f >> 3, col = (f & 7) * 4;
    *(float4*)&Ks[row * 32 + col] = *(const float4*)&kb[(size_t)(b * Sn + k0 + row) * 32 + col];
    *(float4*)&Vs[row * 32 + col] = *(const float4*)&vb[(size_t)(b * Sn + k0 + row) * 32 + col];
  }
  const int q = b * Sn + qhalf * 256 + tid;
  float qv[32];
#pragma unroll
  for (int d4 = 0; d4 < 8; ++d4) {
    float4 v = *(const float4*)&qb[(size_t)q * 32 + d4 * 4];
    qv[d4 * 4 + 0] = v.x; qv[d4 * 4 + 1] = v.y; qv[d4 * 4 + 2] = v.z; qv[d4 * 4 + 3] = v.w;
  }
  __syncthreads();
  const float scale = 0.17677669529663687f;
  float m = -1e30f, lsum = 0.f;
  float acc[32] = {};
  for (int kk = 0; kk < 128; ++kk) {
    const float4* kr = (const float4*)&Ks[kk * 32];
    float s = 0.f;
#pragma unroll
    for (int d4 = 0; d4 < 8; ++d4) {
      float4 kv = kr[d4];
      s += qv[d4 * 4 + 0] * kv.x + qv[d4 * 4 + 1] * kv.y + qv[d4 * 4 + 2] * kv.z + qv[d4 * 4 + 3] * kv.w;
    }
    s *= scale;
    float mn = fmaxf(m, s);
    float e1 = __expf(m - mn);
    float p = __expf(s - mn);
    lsum = lsum * e1 + p;
    const float4* vr = (const float4*)&Vs[kk * 32];
#pragma unroll
    for (int d4 = 0; d4 < 8; ++d4) {
      float4 vv = vr[d4];
      acc[d4 * 4 + 0] = acc[d4 * 4 + 0] * e1 + p * vv.x;
      acc[d4 * 4 + 1] = acc[d4 * 4 + 1] * e1 + p * vv.y;
      acc[d4 * 4 + 2] = acc[d4 * 4 + 2] * e1 + p * vv.z;
      acc[d4 * 4 + 3] = acc[d4 * 4 + 3] * e1 + p * vv.w;
    }
    m = mn;
  }
  float* rec = part + ((size_t)q * 4 + split) * 36;
#pragma unroll
  for (int d4 = 0; d4 < 8; ++d4) {
    float4 o = {acc[d4 * 4 + 0], acc[d4 * 4 + 1], acc[d4 * 4 + 2], acc[d4 * 4 + 3]};
    *(float4*)&rec[d4 * 4] = o;
  }
  rec[32] = m;
  rec[33] = lsum;
}

// ---------------- K4b: combine partials + out_proj ---------------------------
__global__ __launch_bounds__(256) void attn_combine(const float* __restrict__ part,
                                                    const float* __restrict__ Wout,
                                                    const float* __restrict__ bout,
                                                    float* __restrict__ attn) {
  __shared__ float Ws[32 * 32];
  __shared__ float bs[32];
  const int tid = threadIdx.x;
  for (int i = tid; i < 1024; i += 256) Ws[i] = Wout[i];
  if (tid < 32) bs[tid] = bout[tid];
  __syncthreads();
  const int q = blockIdx.x * 256 + tid;
  const float* rec = part + (size_t)q * 4 * 36;
  float m0 = rec[32], m1 = rec[36 + 32], m2 = rec[72 + 32], m3 = rec[108 + 32];
  float M = fmaxf(fmaxf(m0, m1), fmaxf(m2, m3));
  float w0 = __expf(m0 - M), w1 = __expf(m1 - M), w2 = __expf(m2 - M), w3 = __expf(m3 - M);
  float L = rec[33] * w0 + rec[36 + 33] * w1 + rec[72 + 33] * w2 + rec[108 + 33] * w3;
  float inv = 1.f / L;
  float a[32];
#pragma unroll
  for (int d4 = 0; d4 < 8; ++d4) {
    float4 p0 = *(const float4*)&rec[d4 * 4];
    float4 p1 = *(const float4*)&rec[36 + d4 * 4];
    float4 p2 = *(const float4*)&rec[72 + d4 * 4];
    float4 p3 = *(const float4*)&rec[108 + d4 * 4];
    a[d4 * 4 + 0] = (p0.x * w0 + p1.x * w1 + p2.x * w2 + p3.x * w3) * inv;
    a[d4 * 4 + 1] = (p0.y * w0 + p1.y * w1 + p2.y * w2 + p3.y * w3) * inv;
    a[d4 * 4 + 2] = (p0.z * w0 + p1.z * w1 + p2.z * w2 + p3.z * w3) * inv;
    a[d4 * 4 + 3] = (p0.w * w0 + p1.w * w1 + p2.w * w2 + p3.w * w3) * inv;
  }
#pragma unroll
  for (int j = 0; j < 32; ++j) {
    float o = bs[j];
#pragma unroll
    for (int d = 0; d < 32; ++d) o += a[d] * Ws[j * 32 + d];
    attn[(size_t)q * 32 + j] = o;
  }
}

// ---------------- K5: Wcomb = Wdense(128x16) @ Wfuse_top(16x16) --------------
__global__ __launch_bounds__(256) void wcomb_kernel(const float* __restrict__ Wdense,
                                                    const float* __restrict__ Wfuse,
                                                    float* __restrict__ wcomb) {
  int e = blockIdx.x * 256 + threadIdx.x;
  int i = e >> 4, j = e & 15;
  float a = 0.f;
#pragma unroll
  for (int c = 0; c < 16; ++c) a += Wdense[i * 16 + c] * Wfuse[c * 16 + j];
  wcomb[e] = a;
}

// ---------------- K6: emissions ----------------------------------------------
__global__ __launch_bounds__(256) void emis_kernel(const float* __restrict__ lstm,
                                                   const float* __restrict__ attn,
                                                   const float* __restrict__ wcomb,
                                                   const float* __restrict__ Wfuse,
                                                   float* __restrict__ emis) {
  __shared__ float Wc[128 * 16];
  __shared__ float Wf2[32 * 16];
  const int tid = threadIdx.x;
  for (int i = tid; i < 2048; i += 256) Wc[i] = wcomb[i];
  for (int i = tid; i < 512; i += 256) Wf2[i] = Wfuse[16 * 16 + i];
  __syncthreads();
  const int idx = blockIdx.x * 256 + tid;
  float acc[16] = {};
  for (int i = 0; i < 128; i += 4) {
    float4 lv = *(const float4*)&lstm[(size_t)idx * 128 + i];
    float ll[4] = {lv.x, lv.y, lv.z, lv.w};
#pragma unroll
    for (int u = 0; u < 4; ++u)
#pragma unroll
      for (int j = 0; j < 16; ++j) acc[j] += ll[u] * Wc[(i + u) * 16 + j];
  }
  for (int d = 0; d < 32; d += 4) {
    float4 av = *(const float4*)&attn[(size_t)idx * 32 + d];
    float aa[4] = {av.x, av.y, av.z, av.w};
#pragma unroll
    for (int u = 0; u < 4; ++u)
#pragma unroll
      for (int j = 0; j < 16; ++j) acc[j] += aa[u] * Wf2[(d + u) * 16 + j];
  }
#pragma unroll
  for (int j = 0; j < 16; j += 4) {
    float4 o = {acc[j], acc[j + 1], acc[j + 2], acc[j + 3]};
    *(float4*)&emis[(size_t)idx * 16 + j] = o;
  }
}

// ---------------- K7: CRF numerator ------------------------------------------
__global__ __launch_bounds__(64) void numer_kernel(const float* __restrict__ emis,
                                                   const int* __restrict__ tgt,
                                                   const float* __restrict__ cstart,
                                                   const float* __restrict__ cend,
                                                   const float* __restrict__ ctrans,
                                                   float* __restrict__ numer) {
  const int b = blockIdx.x, l = threadIdx.x;
  float ssum = 0.f;
  for (int t = l; t < Sn; t += 64) {
    int tg = tgt[b * Sn + t];
    ssum += emis[(size_t)(b * Sn + t) * Tn + tg];
    if (t + 1 < Sn) {
      int tg2 = tgt[b * Sn + t + 1];
      ssum += ctrans[tg * Tn + tg2];
    }
  }
  if (l == 0) ssum += cstart[tgt[b * Sn]] + cend[tgt[b * Sn + Sn - 1]];
  for (int off = 32; off > 0; off >>= 1) ssum += __shfl_down(ssum, off);
  if (l == 0) numer[b] = ssum;
}

// ---------------- K8: CRF forward (denominator), shfl-only --------------------
__global__ __launch_bounds__(64) void denom_kernel(const float* __restrict__ emis,
                                                   const float* __restrict__ cstart,
                                                   const float* __restrict__ cend,
                                                   const float* __restrict__ ctrans,
                                                   float* __restrict__ denom) {
  const int b = blockIdx.x;
  const int lane = threadIdx.x;
  const int g = lane >> 4;
  const int j = lane & 15;
  const int i0 = 4 * g;
  float tr0 = ctrans[(i0 + 0) * Tn + j];
  float tr1 = ctrans[(i0 + 1) * Tn + j];
  float tr2 = ctrans[(i0 + 2) * Tn + j];
  float tr3 = ctrans[(i0 + 3) * Tn + j];
  float s = cstart[j] + emis[(size_t)(b * Sn) * Tn + j];
  float em = emis[(size_t)(b * Sn + 1) * Tn + j];
  for (int t = 1; t < Sn; ++t) {
    float s0 = __shfl(s, i0 + 0);
    float s1 = __shfl(s, i0 + 1);
    float s2 = __shfl(s, i0 + 2);
    float s3 = __shfl(s, i0 + 3);
    float v0 = s0 + tr0, v1 = s1 + tr1, v2 = s2 + tr2, v3 = s3 + tr3;
    float m = fmaxf(fmaxf(v0, v1), fmaxf(v2, v3));
    m = fmaxf(m, __shfl_xor(m, 16));
    m = fmaxf(m, __shfl_xor(m, 32));
    float e = __expf(v0 - m) + __expf(v1 - m) + __expf(v2 - m) + __expf(v3 - m);
    e += __shfl_xor(e, 16);
    e += __shfl_xor(e, 32);
    float em_cur = em;
    if (t + 1 < Sn) em = emis[(size_t)(b * Sn + t + 1) * Tn + j];
    s = em_cur + m + __logf(e);
  }
  float f = s + cend[j];
  float m = f;
  m = fmaxf(m, __shfl_xor(m, 1));
  m = fmaxf(m, __shfl_xor(m, 2));
  m = fmaxf(m, __shfl_xor(m, 4));
  m = fmaxf(m, __shfl_xor(m, 8));
  float e = __expf(f - m);
  e += __shfl_xor(e, 1);
  e += __shfl_xor(e, 2);
  e += __shfl_xor(e, 4);
  e += __shfl_xor(e, 8);
  if (lane == 0) denom[b] = m + __logf(e);
}

// ---------------- K9: final scalar -------------------------------------------
__global__ __launch_bounds__(64) void final_kernel(const float* __restrict__ numer,
                                                   const float* __restrict__ denom,
                                                   float* __restrict__ out) {
  const int l = threadIdx.x;
  float d = denom[l] - numer[l];
  for (int off = 32; off > 0; off >>= 1) d += __shfl_down(d, off);
  if (l == 0) out[0] = d * (1.f / 64.f);
}

extern "C" void kernel_launch(void* const* d_in, const int* in_sizes, int n_in,
                              void* d_out, int out_size, void* d_ws, size_t ws_size,
                              hipStream_t stream) {
  (void)in_sizes; (void)n_in; (void)out_size; (void)ws_size;
  const float* bert = (const float*)d_in[0];
  const float* in2 = (const float*)d_in[1];
  const int* tgt = (const int*)d_in[2];
  const float* Wih_f = (const float*)d_in[3];
  const float* Whh_f = (const float*)d_in[4];
  const float* bih_f = (const float*)d_in[5];
  const float* bhh_f = (const float*)d_in[6];
  const float* Wih_b = (const float*)d_in[7];
  const float* Whh_b = (const float*)d_in[8];
  const float* bih_b = (const float*)d_in[9];
  const float* bhh_b = (const float*)d_in[10];
  const float* Wdense = (const float*)d_in[11];
  const float* in_proj_w = (const float*)d_in[12];
  const float* in_proj_b = (const float*)d_in[13];
  const float* out_proj_w = (const float*)d_in[14];
  const float* out_proj_b = (const float*)d_in[15];
  const float* Wfuse = (const float*)d_in[16];
  const float* cstart = (const float*)d_in[17];
  const float* cend = (const float*)d_in[18];
  const float* ctrans = (const float*)d_in[19];

  float* ws = (float*)d_ws;
  float* C = ws;                                    // B*S*384 (dead after gru -> reused for attn partials)
  float* lstm = C + (size_t)Bn * Sn * 384;          // B*S*128
  float* qb = lstm + (size_t)Bn * Sn * 2 * Hn;      // B*S*32
  float* kb = qb + (size_t)Bn * Sn * Pn;
  float* vb = kb + (size_t)Bn * Sn * Pn;
  float* attn = vb + (size_t)Bn * Sn * Pn;
  float* emis = attn + (size_t)Bn * Sn * Pn;        // B*S*16
  float* wcomb = emis + (size_t)Bn * Sn * Tn;       // 2048
  float* numer = wcomb + 128 * 16;                  // 64
  float* denom = numer + Bn;                        // 64
  float* part = C;                                  // 32768*4*36 floats (18.9 MB) < C (50 MB)

  dim3 gg(3, Bn * Sn / 128);
  gemm_mfma<<<gg, 256, 0, stream>>>(bert, Wih_f, Wih_b, bih_f, bih_b, C);
  qkv_kernel<<<Bn * Sn / 256, 256, 0, stream>>>(in2, in_proj_w, in_proj_b, qb, kb, vb);
  wcomb_kernel<<<8, 256, 0, stream>>>(Wdense, Wfuse, wcomb);
  gru_kernel<<<2 * Bn, 64, 0, stream>>>(C, Whh_f, bhh_f, Whh_b, bhh_b, lstm);
  attn_split<<<Bn * 8, 256, 0, stream>>>(qb, kb, vb, part);
  attn_combine<<<Bn * Sn / 256, 256, 0, stream>>>(part, out_proj_w, out_proj_b, attn);
  emis_kernel<<<Bn * Sn / 256, 256, 0, stream>>>(lstm, attn, wcomb, Wfuse, emis);
  numer_kernel<<<Bn, 64, 0, stream>>>(emis, tgt, cstart, cend, ctrans, numer);
  denom_kernel<<<Bn, 64, 0, stream>>>(emis, cstart, cend, ctrans, denom);
  final_kernel<<<1, 64, 0, stream>>>(numer, denom, (float*)d_out);
}

// Round 8
// 732.970 us; speedup vs baseline: 1.2976x; 1.2976x over previous
//
#include <hip/hip_runtime.h>

#define Bn 64
#define Sn 512
#define EB 768
#define Hn 64
#define G3 192
#define Tn 16
#define Pn 32

__device__ __forceinline__ float sigmoidf_(float x) { return 1.f / (1.f + __expf(-x)); }
__device__ __forceinline__ float tanhf_(float x) { return 1.f - 2.f / (__expf(2.f * x) + 1.f); }

__device__ __forceinline__ unsigned short f2bf(float x) {
  union { float f; unsigned u; } v; v.f = x;
  unsigned r = v.u + 0x7fff + ((v.u >> 16) & 1);  // RNE
  return (unsigned short)(r >> 16);
}

typedef __attribute__((ext_vector_type(8))) short short8;
typedef __attribute__((ext_vector_type(4))) float f32x4;

// ---------------- K1: C(32768x384) = bert(32768x768) @ [Wf;Wb]^T + bias, bf16 MFMA
// 1-D grid 768 with XCD-sibling swizzle: the 3 n-tiles sharing one A m-tile
// land on the SAME XCD (blk%8 = XCD round-robin) -> A fetched ~once from HBM.
__global__ __launch_bounds__(256) void gemm_mfma(const float* __restrict__ A,
                                                 const float* __restrict__ Wf,
                                                 const float* __restrict__ Wb,
                                                 const float* __restrict__ bf,
                                                 const float* __restrict__ bb,
                                                 float* __restrict__ C) {
  __shared__ __align__(16) unsigned short As[128 * 40];
  __shared__ __align__(16) unsigned short Bs[128 * 40];
  const int g = blockIdx.x;          // 0..767
  const int xcd = g & 7;
  const int slot = g >> 3;           // 0..95
  const int lin = xcd * 96 + slot;   // siblings lin=3m..3m+2 share an XCD
  const int m_tile = lin / 3;
  const int n_tile = lin % 3;
  const int n0 = n_tile * 128;
  const int m0 = m_tile * 128;
  const int tid = threadIdx.x;
  const int wv = tid >> 6;
  const int lane = tid & 63;
  const int wm = (wv >> 1) * 64, wn = (wv & 1) * 64;
  const int fr = lane & 15, fq = lane >> 4;
  const int srow = tid >> 1;
  const int shalf = (tid & 1) * 16;
  const int bcol = n0 + srow;
  const float* Wrow = (bcol < G3) ? (Wf + (size_t)bcol * EB) : (Wb + (size_t)(bcol - G3) * EB);
  const float* Arow = A + (size_t)(m0 + srow) * EB;
  f32x4 acc[4][4];
#pragma unroll
  for (int i = 0; i < 4; ++i)
#pragma unroll
    for (int j = 0; j < 4; ++j) acc[i][j] = (f32x4){0.f, 0.f, 0.f, 0.f};

  for (int k0 = 0; k0 < EB; k0 += 32) {
    float4 a0 = *(const float4*)&Arow[k0 + shalf + 0];
    float4 a1 = *(const float4*)&Arow[k0 + shalf + 4];
    float4 a2 = *(const float4*)&Arow[k0 + shalf + 8];
    float4 a3 = *(const float4*)&Arow[k0 + shalf + 12];
    float4 b0 = *(const float4*)&Wrow[k0 + shalf + 0];
    float4 b1 = *(const float4*)&Wrow[k0 + shalf + 4];
    float4 b2 = *(const float4*)&Wrow[k0 + shalf + 8];
    float4 b3 = *(const float4*)&Wrow[k0 + shalf + 12];
    __syncthreads();
    short8 pa, pb;
    pa[0] = f2bf(a0.x); pa[1] = f2bf(a0.y); pa[2] = f2bf(a0.z); pa[3] = f2bf(a0.w);
    pa[4] = f2bf(a1.x); pa[5] = f2bf(a1.y); pa[6] = f2bf(a1.z); pa[7] = f2bf(a1.w);
    *(short8*)&As[srow * 40 + shalf] = pa;
    pa[0] = f2bf(a2.x); pa[1] = f2bf(a2.y); pa[2] = f2bf(a2.z); pa[3] = f2bf(a2.w);
    pa[4] = f2bf(a3.x); pa[5] = f2bf(a3.y); pa[6] = f2bf(a3.z); pa[7] = f2bf(a3.w);
    *(short8*)&As[srow * 40 + shalf + 8] = pa;
    pb[0] = f2bf(b0.x); pb[1] = f2bf(b0.y); pb[2] = f2bf(b0.z); pb[3] = f2bf(b0.w);
    pb[4] = f2bf(b1.x); pb[5] = f2bf(b1.y); pb[6] = f2bf(b1.z); pb[7] = f2bf(b1.w);
    *(short8*)&Bs[srow * 40 + shalf] = pb;
    pb[0] = f2bf(b2.x); pb[1] = f2bf(b2.y); pb[2] = f2bf(b2.z); pb[3] = f2bf(b2.w);
    pb[4] = f2bf(b3.x); pb[5] = f2bf(b3.y); pb[6] = f2bf(b3.z); pb[7] = f2bf(b3.w);
    *(short8*)&Bs[srow * 40 + shalf + 8] = pb;
    __syncthreads();
    short8 af[4], bfv[4];
#pragma unroll
    for (int i = 0; i < 4; ++i) af[i] = *(short8*)&As[(wm + i * 16 + fr) * 40 + fq * 8];
#pragma unroll
    for (int j = 0; j < 4; ++j) bfv[j] = *(short8*)&Bs[(wn + j * 16 + fr) * 40 + fq * 8];
#pragma unroll
    for (int i = 0; i < 4; ++i)
#pragma unroll
      for (int j = 0; j < 4; ++j)
        acc[i][j] = __builtin_amdgcn_mfma_f32_16x16x32_bf16(af[i], bfv[j], acc[i][j], 0, 0, 0);
  }
#pragma unroll
  for (int j = 0; j < 4; ++j) {
    int col = n0 + wn + j * 16 + fr;
    float bias = (col < G3) ? bf[col] : bb[col - G3];
#pragma unroll
    for (int i = 0; i < 4; ++i) {
      int rowb = m0 + wm + i * 16 + fq * 4;
#pragma unroll
      for (int rg = 0; rg < 4; ++rg)
        C[(size_t)(rowb + rg) * 384 + col] = acc[i][j][rg] + bias;
    }
  }
}

// ---------------- K2: Bi-GRU, 4 waves per (b,dir), chunked LDS x-staging ------
// (R5 version — best measured: 230 µs. 48 weight floats/lane stays in VGPRs;
//  >64/lane provably gets AGPR'd by the allocator and regresses.)
__global__ __launch_bounds__(256, 1) void gru_kernel(const float* __restrict__ C,
                                                     const float* __restrict__ Whh_f,
                                                     const float* __restrict__ bhh_f,
                                                     const float* __restrict__ Whh_b,
                                                     const float* __restrict__ bhh_b,
                                                     float* __restrict__ out) {
  __shared__ __align__(16) float xs[32 * 192];   // 24.5 KB x-chunk
  __shared__ __align__(16) float hbuf[2][64];
  __shared__ __align__(16) float obuf[32 * 64];  // 8 KB h-out buffer
  const int wg = blockIdx.x;
  const int rev = (wg >= Bn) ? 1 : 0;
  const int b = wg & (Bn - 1);
  const int tid = threadIdx.x;
  const int w = tid >> 6;
  const int lane = tid & 63;
  const int r = lane >> 2;
  const int kc = lane & 3;
  const int row = 16 * w + r;
  const int k0 = 16 * kc;
  const float* Whh = rev ? Whh_b : Whh_f;
  const float* bhh = rev ? bhh_b : bhh_f;
  const int colBase = rev ? G3 : 0;
  const int dirOff = rev ? Hn : 0;
  float4 wv[3][4];
#pragma unroll
  for (int g = 0; g < 3; ++g)
#pragma unroll
    for (int q = 0; q < 4; ++q) {
      wv[g][q] = *(const float4*)&Whh[(size_t)(g * 64 + row) * 64 + k0 + 4 * q];
      asm volatile("" : "+v"(wv[g][q].x), "+v"(wv[g][q].y), "+v"(wv[g][q].z), "+v"(wv[g][q].w));
    }
  const float brr = bhh[row], bzz = bhh[64 + row], bnn = bhh[128 + row];
  if (tid < 64) { hbuf[0][tid] = 0.f; hbuf[1][tid] = 0.f; }
  float h = 0.f;
  for (int c = 0; c < 16; ++c) {
    const int cstart = c * 32;
    if (c > 0) {
#pragma unroll
      for (int i = 0; i < 2; ++i) {
        int f = tid + 256 * i;
        int s = f >> 4;
        int c4 = (f & 15) << 2;
        int tp = cstart - 32 + s;
        int orow = rev ? (Sn - 1 - tp) : tp;
        *(float4*)&out[(size_t)(b * Sn + orow) * 128 + dirOff + c4] = *(const float4*)&obuf[s * 64 + c4];
      }
    }
    float4 st[6];
#pragma unroll
    for (int i = 0; i < 6; ++i) {
      int f = tid + 256 * i;
      int s = f / 48;
      int c4 = (f % 48) << 2;
      int t = cstart + s;
      int grow = rev ? (Sn - 1 - t) : t;
      st[i] = *(const float4*)&C[(size_t)(b * Sn + grow) * 384 + colBase + c4];
    }
#pragma unroll
    for (int i = 0; i < 6; ++i) {
      int f = tid + 256 * i;
      int s = f / 48;
      int c4 = (f % 48) << 2;
      *(float4*)&xs[s * 192 + c4] = st[i];
    }
    __syncthreads();
    float xr = xs[row], xz = xs[64 + row], xn = xs[128 + row];
    for (int s = 0; s < 32; ++s) {
      const int t = cstart + s;
      const int p = t & 1;
      float4 ha = *(const float4*)&hbuf[p][k0 + 0];
      float4 hb = *(const float4*)&hbuf[p][k0 + 4];
      float4 hc = *(const float4*)&hbuf[p][k0 + 8];
      float4 hd = *(const float4*)&hbuf[p][k0 + 12];
      float nxr = 0.f, nxz = 0.f, nxn = 0.f;
      if (s + 1 < 32) {
        const float* xq = &xs[(s + 1) * 192];
        nxr = xq[row]; nxz = xq[64 + row]; nxn = xq[128 + row];
      }
      float dr, dz, dn;
      {
        float4 wa, wbv, wc, wd;
        wa = wv[0][0]; wbv = wv[0][1]; wc = wv[0][2]; wd = wv[0][3];
        dr = (wa.x * ha.x + wa.y * ha.y + wa.z * ha.z + wa.w * ha.w)
           + (wbv.x * hb.x + wbv.y * hb.y + wbv.z * hb.z + wbv.w * hb.w)
           + (wc.x * hc.x + wc.y * hc.y + wc.z * hc.z + wc.w * hc.w)
           + (wd.x * hd.x + wd.y * hd.y + wd.z * hd.z + wd.w * hd.w);
        wa = wv[1][0]; wbv = wv[1][1]; wc = wv[1][2]; wd = wv[1][3];
        dz = (wa.x * ha.x + wa.y * ha.y + wa.z * ha.z + wa.w * ha.w)
           + (wbv.x * hb.x + wbv.y * hb.y + wbv.z * hb.z + wbv.w * hb.w)
           + (wc.x * hc.x + wc.y * hc.y + wc.z * hc.z + wc.w * hc.w)
           + (wd.x * hd.x + wd.y * hd.y + wd.z * hd.z + wd.w * hd.w);
        wa = wv[2][0]; wbv = wv[2][1]; wc = wv[2][2]; wd = wv[2][3];
        dn = (wa.x * ha.x + wa.y * ha.y + wa.z * ha.z + wa.w * ha.w)
           + (wbv.x * hb.x + wbv.y * hb.y + wbv.z * hb.z + wbv.w * hb.w)
           + (wc.x * hc.x + wc.y * hc.y + wc.z * hc.z + wc.w * hc.w)
           + (wd.x * hd.x + wd.y * hd.y + wd.z * hd.z + wd.w * hd.w);
      }
      dr += __shfl_xor(dr, 1); dr += __shfl_xor(dr, 2);
      dz += __shfl_xor(dz, 1); dz += __shfl_xor(dz, 2);
      dn += __shfl_xor(dn, 1); dn += __shfl_xor(dn, 2);
      float rg = sigmoidf_(xr + brr + dr);
      float zg = sigmoidf_(xz + bzz + dz);
      float ng = tanhf_(xn + rg * (bnn + dn));
      h = (1.f - zg) * ng + zg * h;
      if (kc == 0) {
        hbuf[p ^ 1][row] = h;
        obuf[s * 64 + row] = h;
      }
      __syncthreads();
      xr = nxr; xz = nxz; xn = nxn;
    }
  }
#pragma unroll
  for (int i = 0; i < 2; ++i) {
    int f = tid + 256 * i;
    int s = f >> 4;
    int c4 = (f & 15) << 2;
    int tp = Sn - 32 + s;
    int orow = rev ? (Sn - 1 - tp) : tp;
    *(float4*)&out[(size_t)(b * Sn + orow) * 128 + dirOff + c4] = *(const float4*)&obuf[s * 64 + c4];
  }
}

// ---------------- K3: qkv projection (3 passes, float4 stores) ----------------
__global__ __launch_bounds__(256) void qkv_kernel(const float* __restrict__ in2,
                                                  const float* __restrict__ Wqkv,
                                                  const float* __restrict__ bqkv,
                                                  float* __restrict__ qb,
                                                  float* __restrict__ kb,
                                                  float* __restrict__ vb) {
  __shared__ float Ws[96 * 32];
  __shared__ float bs[96];
  const int tid = threadIdx.x;
  for (int i = tid; i < 96 * 32; i += 256) Ws[i] = Wqkv[i];
  if (tid < 96) bs[tid] = bqkv[tid];
  __syncthreads();
  const int idx = blockIdx.x * 256 + tid;
  float x[32];
#pragma unroll
  for (int d4 = 0; d4 < 8; ++d4) {
    float4 v = *(const float4*)&in2[(size_t)idx * 32 + d4 * 4];
    x[d4 * 4 + 0] = v.x; x[d4 * 4 + 1] = v.y; x[d4 * 4 + 2] = v.z; x[d4 * 4 + 3] = v.w;
  }
  float* const dsts[3] = {qb, kb, vb};
#pragma unroll
  for (int p = 0; p < 3; ++p) {
    float a[32];
#pragma unroll
    for (int j = 0; j < 32; ++j) {
      float s = bs[p * 32 + j];
#pragma unroll
      for (int d = 0; d < 32; ++d) s += x[d] * Ws[(p * 32 + j) * 32 + d];
      a[j] = s;
    }
    float* dst = dsts[p];
#pragma unroll
    for (int j4 = 0; j4 < 8; ++j4) {
      float4 o = {a[j4 * 4 + 0], a[j4 * 4 + 1], a[j4 * 4 + 2], a[j4 * 4 + 3]};
      *(float4*)&dst[(size_t)idx * 32 + j4 * 4] = o;
    }
  }
}

// ---------------- K4a: attention split-K partial (flash-style) ----------------
__global__ __launch_bounds__(256) void attn_split(const float* __restrict__ qb,
                                                  const float* __restrict__ kb,
                                                  const float* __restrict__ vb,
                                                  float* __restrict__ part) {
  __shared__ __align__(16) float Ks[128 * 32];
  __shared__ __align__(16) float Vs[128 * 32];
  const int tid = threadIdx.x;
  const int blk = blockIdx.x;
  const int b = blk >> 3;
  const int qhalf = (blk >> 2) & 1;
  const int split = blk & 3;
  const int k0 = split * 128;
#pragma unroll
  for (int i = 0; i < 4; ++i) {
    int f = tid + 256 * i;
    int row = f >> 3, col = (f & 7) * 4;
    *(float4*)&Ks[row * 32 + col] = *(const float4*)&kb[(size_t)(b * Sn + k0 + row) * 32 + col];
    *(float4*)&Vs[row * 32 + col] = *(const float4*)&vb[(size_t)(b * Sn + k0 + row) * 32 + col];
  }
  const int q = b * Sn + qhalf * 256 + tid;
  float qv[32];
#pragma unroll
  for (int d4 = 0; d4 < 8; ++d4) {
    float4 v = *(const float4*)&qb[(size_t)q * 32 + d4 * 4];
    qv[d4 * 4 + 0] = v.x; qv[d4 * 4 + 1] = v.y; qv[d4 * 4 + 2] = v.z; qv[d4 * 4 + 3] = v.w;
  }
  __syncthreads();
  const float scale = 0.17677669529663687f;
  float m = -1e30f, lsum = 0.f;
  float acc[32] = {};
  for (int kk = 0; kk < 128; ++kk) {
    const float4* kr = (const float4*)&Ks[kk * 32];
    float s = 0.f;
#pragma unroll
    for (int d4 = 0; d4 < 8; ++d4) {
      float4 kv = kr[d4];
      s += qv[d4 * 4 + 0] * kv.x + qv[d4 * 4 + 1] * kv.y + qv[d4 * 4 + 2] * kv.z + qv[d4 * 4 + 3] * kv.w;
    }
    s *= scale;
    float mn = fmaxf(m, s);
    float e1 = __expf(m - mn);
    float p = __expf(s - mn);
    lsum = lsum * e1 + p;
    const float4* vr = (const float4*)&Vs[kk * 32];
#pragma unroll
    for (int d4 = 0; d4 < 8; ++d4) {
      float4 vv = vr[d4];
      acc[d4 * 4 + 0] = acc[d4 * 4 + 0] * e1 + p * vv.x;
      acc[d4 * 4 + 1] = acc[d4 * 4 + 1] * e1 + p * vv.y;
      acc[d4 * 4 + 2] = acc[d4 * 4 + 2] * e1 + p * vv.z;
      acc[d4 * 4 + 3] = acc[d4 * 4 + 3] * e1 + p * vv.w;
    }
    m = mn;
  }
  float* rec = part + ((size_t)q * 4 + split) * 36;
#pragma unroll
  for (int d4 = 0; d4 < 8; ++d4) {
    float4 o = {acc[d4 * 4 + 0], acc[d4 * 4 + 1], acc[d4 * 4 + 2], acc[d4 * 4 + 3]};
    *(float4*)&rec[d4 * 4] = o;
  }
  rec[32] = m;
  rec[33] = lsum;
}

// ---------------- K4b: combine partials + out_proj ---------------------------
__global__ __launch_bounds__(256) void attn_combine(const float* __restrict__ part,
                                                    const float* __restrict__ Wout,
                                                    const float* __restrict__ bout,
                                                    float* __restrict__ attn) {
  __shared__ float Ws[32 * 32];
  __shared__ float bs[32];
  const int tid = threadIdx.x;
  for (int i = tid; i < 1024; i += 256) Ws[i] = Wout[i];
  if (tid < 32) bs[tid] = bout[tid];
  __syncthreads();
  const int q = blockIdx.x * 256 + tid;
  const float* rec = part + (size_t)q * 4 * 36;
  float m0 = rec[32], m1 = rec[36 + 32], m2 = rec[72 + 32], m3 = rec[108 + 32];
  float M = fmaxf(fmaxf(m0, m1), fmaxf(m2, m3));
  float w0 = __expf(m0 - M), w1 = __expf(m1 - M), w2 = __expf(m2 - M), w3 = __expf(m3 - M);
  float L = rec[33] * w0 + rec[36 + 33] * w1 + rec[72 + 33] * w2 + rec[108 + 33] * w3;
  float inv = 1.f / L;
  float a[32];
#pragma unroll
  for (int d4 = 0; d4 < 8; ++d4) {
    float4 p0 = *(const float4*)&rec[d4 * 4];
    float4 p1 = *(const float4*)&rec[36 + d4 * 4];
    float4 p2 = *(const float4*)&rec[72 + d4 * 4];
    float4 p3 = *(const float4*)&rec[108 + d4 * 4];
    a[d4 * 4 + 0] = (p0.x * w0 + p1.x * w1 + p2.x * w2 + p3.x * w3) * inv;
    a[d4 * 4 + 1] = (p0.y * w0 + p1.y * w1 + p2.y * w2 + p3.y * w3) * inv;
    a[d4 * 4 + 2] = (p0.z * w0 + p1.z * w1 + p2.z * w2 + p3.z * w3) * inv;
    a[d4 * 4 + 3] = (p0.w * w0 + p1.w * w1 + p2.w * w2 + p3.w * w3) * inv;
  }
#pragma unroll
  for (int j = 0; j < 32; ++j) {
    float o = bs[j];
#pragma unroll
    for (int d = 0; d < 32; ++d) o += a[d] * Ws[j * 32 + d];
    attn[(size_t)q * 32 + j] = o;
  }
}

// ---------------- K5: Wcomb = Wdense(128x16) @ Wfuse_top(16x16) --------------
__global__ __launch_bounds__(256) void wcomb_kernel(const float* __restrict__ Wdense,
                                                    const float* __restrict__ Wfuse,
                                                    float* __restrict__ wcomb) {
  int e = blockIdx.x * 256 + threadIdx.x;
  int i = e >> 4, j = e & 15;
  float a = 0.f;
#pragma unroll
  for (int c = 0; c < 16; ++c) a += Wdense[i * 16 + c] * Wfuse[c * 16 + j];
  wcomb[e] = a;
}

// ---------------- K6: emissions ----------------------------------------------
__global__ __launch_bounds__(256) void emis_kernel(const float* __restrict__ lstm,
                                                   const float* __restrict__ attn,
                                                   const float* __restrict__ wcomb,
                                                   const float* __restrict__ Wfuse,
                                                   float* __restrict__ emis) {
  __shared__ float Wc[128 * 16];
  __shared__ float Wf2[32 * 16];
  const int tid = threadIdx.x;
  for (int i = tid; i < 2048; i += 256) Wc[i] = wcomb[i];
  for (int i = tid; i < 512; i += 256) Wf2[i] = Wfuse[16 * 16 + i];
  __syncthreads();
  const int idx = blockIdx.x * 256 + tid;
  float acc[16] = {};
  for (int i = 0; i < 128; i += 4) {
    float4 lv = *(const float4*)&lstm[(size_t)idx * 128 + i];
    float ll[4] = {lv.x, lv.y, lv.z, lv.w};
#pragma unroll
    for (int u = 0; u < 4; ++u)
#pragma unroll
      for (int j = 0; j < 16; ++j) acc[j] += ll[u] * Wc[(i + u) * 16 + j];
  }
  for (int d = 0; d < 32; d += 4) {
    float4 av = *(const float4*)&attn[(size_t)idx * 32 + d];
    float aa[4] = {av.x, av.y, av.z, av.w};
#pragma unroll
    for (int u = 0; u < 4; ++u)
#pragma unroll
      for (int j = 0; j < 16; ++j) acc[j] += aa[u] * Wf2[(d + u) * 16 + j];
  }
#pragma unroll
  for (int j = 0; j < 16; j += 4) {
    float4 o = {acc[j], acc[j + 1], acc[j + 2], acc[j + 3]};
    *(float4*)&emis[(size_t)idx * 16 + j] = o;
  }
}

// ---------------- K7: CRF numerator ------------------------------------------
__global__ __launch_bounds__(64) void numer_kernel(const float* __restrict__ emis,
                                                   const int* __restrict__ tgt,
                                                   const float* __restrict__ cstart,
                                                   const float* __restrict__ cend,
                                                   const float* __restrict__ ctrans,
                                                   float* __restrict__ numer) {
  const int b = blockIdx.x, l = threadIdx.x;
  float ssum = 0.f;
  for (int t = l; t < Sn; t += 64) {
    int tg = tgt[b * Sn + t];
    ssum += emis[(size_t)(b * Sn + t) * Tn + tg];
    if (t + 1 < Sn) {
      int tg2 = tgt[b * Sn + t + 1];
      ssum += ctrans[tg * Tn + tg2];
    }
  }
  if (l == 0) ssum += cstart[tgt[b * Sn]] + cend[tgt[b * Sn + Sn - 1]];
  for (int off = 32; off > 0; off >>= 1) ssum += __shfl_down(ssum, off);
  if (l == 0) numer[b] = ssum;
}

// ---------------- K8: CRF forward (denominator), shfl-only --------------------
__global__ __launch_bounds__(64) void denom_kernel(const float* __restrict__ emis,
                                                   const float* __restrict__ cstart,
                                                   const float* __restrict__ cend,
                                                   const float* __restrict__ ctrans,
                                                   float* __restrict__ denom) {
  const int b = blockIdx.x;
  const int lane = threadIdx.x;
  const int g = lane >> 4;
  const int j = lane & 15;
  const int i0 = 4 * g;
  float tr0 = ctrans[(i0 + 0) * Tn + j];
  float tr1 = ctrans[(i0 + 1) * Tn + j];
  float tr2 = ctrans[(i0 + 2) * Tn + j];
  float tr3 = ctrans[(i0 + 3) * Tn + j];
  float s = cstart[j] + emis[(size_t)(b * Sn) * Tn + j];
  float em = emis[(size_t)(b * Sn + 1) * Tn + j];
  for (int t = 1; t < Sn; ++t) {
    float s0 = __shfl(s, i0 + 0);
    float s1 = __shfl(s, i0 + 1);
    float s2 = __shfl(s, i0 + 2);
    float s3 = __shfl(s, i0 + 3);
    float v0 = s0 + tr0, v1 = s1 + tr1, v2 = s2 + tr2, v3 = s3 + tr3;
    float m = fmaxf(fmaxf(v0, v1), fmaxf(v2, v3));
    m = fmaxf(m, __shfl_xor(m, 16));
    m = fmaxf(m, __shfl_xor(m, 32));
    float e = __expf(v0 - m) + __expf(v1 - m) + __expf(v2 - m) + __expf(v3 - m);
    e += __shfl_xor(e, 16);
    e += __shfl_xor(e, 32);
    float em_cur = em;
    if (t + 1 < Sn) em = emis[(size_t)(b * Sn + t + 1) * Tn + j];
    s = em_cur + m + __logf(e);
  }
  float f = s + cend[j];
  float m = f;
  m = fmaxf(m, __shfl_xor(m, 1));
  m = fmaxf(m, __shfl_xor(m, 2));
  m = fmaxf(m, __shfl_xor(m, 4));
  m = fmaxf(m, __shfl_xor(m, 8));
  float e = __expf(f - m);
  e += __shfl_xor(e, 1);
  e += __shfl_xor(e, 2);
  e += __shfl_xor(e, 4);
  e += __shfl_xor(e, 8);
  if (lane == 0) denom[b] = m + __logf(e);
}

// ---------------- K9: final scalar -------------------------------------------
__global__ __launch_bounds__(64) void final_kernel(const float* __restrict__ numer,
                                                   const float* __restrict__ denom,
                                                   float* __restrict__ out) {
  const int l = threadIdx.x;
  float d = denom[l] - numer[l];
  for (int off = 32; off > 0; off >>= 1) d += __shfl_down(d, off);
  if (l == 0) out[0] = d * (1.f / 64.f);
}

extern "C" void kernel_launch(void* const* d_in, const int* in_sizes, int n_in,
                              void* d_out, int out_size, void* d_ws, size_t ws_size,
                              hipStream_t stream) {
  (void)in_sizes; (void)n_in; (void)out_size; (void)ws_size;
  const float* bert = (const float*)d_in[0];
  const float* in2 = (const float*)d_in[1];
  const int* tgt = (const int*)d_in[2];
  const float* Wih_f = (const float*)d_in[3];
  const float* Whh_f = (const float*)d_in[4];
  const float* bih_f = (const float*)d_in[5];
  const float* bhh_f = (const float*)d_in[6];
  const float* Wih_b = (const float*)d_in[7];
  const float* Whh_b = (const float*)d_in[8];
  const float* bih_b = (const float*)d_in[9];
  const float* bhh_b = (const float*)d_in[10];
  const float* Wdense = (const float*)d_in[11];
  const float* in_proj_w = (const float*)d_in[12];
  const float* in_proj_b = (const float*)d_in[13];
  const float* out_proj_w = (const float*)d_in[14];
  const float* out_proj_b = (const float*)d_in[15];
  const float* Wfuse = (const float*)d_in[16];
  const float* cstart = (const float*)d_in[17];
  const float* cend = (const float*)d_in[18];
  const float* ctrans = (const float*)d_in[19];

  float* ws = (float*)d_ws;
  float* C = ws;                                    // B*S*384 (dead after gru -> reused for attn partials)
  float* lstm = C + (size_t)Bn * Sn * 384;          // B*S*128
  float* qb = lstm + (size_t)Bn * Sn * 2 * Hn;      // B*S*32
  float* kb = qb + (size_t)Bn * Sn * Pn;
  float* vb = kb + (size_t)Bn * Sn * Pn;
  float* attn = vb + (size_t)Bn * Sn * Pn;
  float* emis = attn + (size_t)Bn * Sn * Pn;        // B*S*16
  float* wcomb = emis + (size_t)Bn * Sn * Tn;       // 2048
  float* numer = wcomb + 128 * 16;                  // 64
  float* denom = numer + Bn;                        // 64
  float* part = C;                                  // 32768*4*36 floats (18.9 MB) < C (50 MB)

  gemm_mfma<<<768, 256, 0, stream>>>(bert, Wih_f, Wih_b, bih_f, bih_b, C);
  qkv_kernel<<<Bn * Sn / 256, 256, 0, stream>>>(in2, in_proj_w, in_proj_b, qb, kb, vb);
  wcomb_kernel<<<8, 256, 0, stream>>>(Wdense, Wfuse, wcomb);
  gru_kernel<<<2 * Bn, 256, 0, stream>>>(C, Whh_f, bhh_f, Whh_b, bhh_b, lstm);
  attn_split<<<Bn * 8, 256, 0, stream>>>(qb, kb, vb, part);
  attn_combine<<<Bn * Sn / 256, 256, 0, stream>>>(part, out_proj_w, out_proj_b, attn);
  emis_kernel<<<Bn * Sn / 256, 256, 0, stream>>>(lstm, attn, wcomb, Wfuse, emis);
  numer_kernel<<<Bn, 64, 0, stream>>>(emis, tgt, cstart, cend, ctrans, numer);
  denom_kernel<<<Bn, 64, 0, stream>>>(emis, cstart, cend, ctrans, denom);
  final_kernel<<<1, 64, 0, stream>>>(numer, denom, (float*)d_out);
}

// Round 9
// 621.149 us; speedup vs baseline: 1.5312x; 1.1800x over previous
//
#include <hip/hip_runtime.h>

#define Bn 64
#define Sn 512
#define EB 768
#define Hn 64
#define G3 192
#define Tn 16
#define Pn 32

__device__ __forceinline__ float sigmoidf_(float x) { return 1.f / (1.f + __expf(-x)); }
__device__ __forceinline__ float tanhf_(float x) { return 1.f - 2.f / (__expf(2.f * x) + 1.f); }

__device__ __forceinline__ unsigned short f2bf(float x) {
  union { float f; unsigned u; } v; v.f = x;
  unsigned r = v.u + 0x7fff + ((v.u >> 16) & 1);  // RNE
  return (unsigned short)(r >> 16);
}

typedef __attribute__((ext_vector_type(8))) short short8;
typedef __attribute__((ext_vector_type(4))) float f32x4;

// ================= K_A: gemm (0..767) + qkv (768..895) + wcomb (896..903) ====
__global__ __launch_bounds__(256) void mega_a(const float* __restrict__ A,
                                              const float* __restrict__ Wf,
                                              const float* __restrict__ Wb,
                                              const float* __restrict__ bf,
                                              const float* __restrict__ bb,
                                              float* __restrict__ C,
                                              const float* __restrict__ in2,
                                              const float* __restrict__ Wqkv,
                                              const float* __restrict__ bqkv,
                                              float* __restrict__ qb,
                                              float* __restrict__ kb,
                                              float* __restrict__ vb,
                                              const float* __restrict__ Wdense,
                                              const float* __restrict__ Wfuse,
                                              float* __restrict__ wcomb) {
  __shared__ __align__(16) char smem[20864];
  const int gblk = blockIdx.x;
  const int tid = threadIdx.x;
  if (gblk < 768) {
    // ---- gemm_mfma: XCD-sibling swizzle (3 n-tiles of one m-tile share an XCD)
    unsigned short* As = (unsigned short*)smem;          // 128*40
    unsigned short* Bs = As + 128 * 40;                  // 128*40
    const int g = gblk;
    const int xcd = g & 7;
    const int slot = g >> 3;
    const int lin = xcd * 96 + slot;
    const int m_tile = lin / 3;
    const int n_tile = lin % 3;
    const int n0 = n_tile * 128;
    const int m0 = m_tile * 128;
    const int wv = tid >> 6;
    const int lane = tid & 63;
    const int wm = (wv >> 1) * 64, wn = (wv & 1) * 64;
    const int fr = lane & 15, fq = lane >> 4;
    const int srow = tid >> 1;
    const int shalf = (tid & 1) * 16;
    const int bcol = n0 + srow;
    const float* Wrow = (bcol < G3) ? (Wf + (size_t)bcol * EB) : (Wb + (size_t)(bcol - G3) * EB);
    const float* Arow = A + (size_t)(m0 + srow) * EB;
    f32x4 acc[4][4];
#pragma unroll
    for (int i = 0; i < 4; ++i)
#pragma unroll
      for (int j = 0; j < 4; ++j) acc[i][j] = (f32x4){0.f, 0.f, 0.f, 0.f};
    for (int k0 = 0; k0 < EB; k0 += 32) {
      float4 a0 = *(const float4*)&Arow[k0 + shalf + 0];
      float4 a1 = *(const float4*)&Arow[k0 + shalf + 4];
      float4 a2 = *(const float4*)&Arow[k0 + shalf + 8];
      float4 a3 = *(const float4*)&Arow[k0 + shalf + 12];
      float4 b0 = *(const float4*)&Wrow[k0 + shalf + 0];
      float4 b1 = *(const float4*)&Wrow[k0 + shalf + 4];
      float4 b2 = *(const float4*)&Wrow[k0 + shalf + 8];
      float4 b3 = *(const float4*)&Wrow[k0 + shalf + 12];
      __syncthreads();
      short8 pa, pb;
      pa[0] = f2bf(a0.x); pa[1] = f2bf(a0.y); pa[2] = f2bf(a0.z); pa[3] = f2bf(a0.w);
      pa[4] = f2bf(a1.x); pa[5] = f2bf(a1.y); pa[6] = f2bf(a1.z); pa[7] = f2bf(a1.w);
      *(short8*)&As[srow * 40 + shalf] = pa;
      pa[0] = f2bf(a2.x); pa[1] = f2bf(a2.y); pa[2] = f2bf(a2.z); pa[3] = f2bf(a2.w);
      pa[4] = f2bf(a3.x); pa[5] = f2bf(a3.y); pa[6] = f2bf(a3.z); pa[7] = f2bf(a3.w);
      *(short8*)&As[srow * 40 + shalf + 8] = pa;
      pb[0] = f2bf(b0.x); pb[1] = f2bf(b0.y); pb[2] = f2bf(b0.z); pb[3] = f2bf(b0.w);
      pb[4] = f2bf(b1.x); pb[5] = f2bf(b1.y); pb[6] = f2bf(b1.z); pb[7] = f2bf(b1.w);
      *(short8*)&Bs[srow * 40 + shalf] = pb;
      pb[0] = f2bf(b2.x); pb[1] = f2bf(b2.y); pb[2] = f2bf(b2.z); pb[3] = f2bf(b2.w);
      pb[4] = f2bf(b3.x); pb[5] = f2bf(b3.y); pb[6] = f2bf(b3.z); pb[7] = f2bf(b3.w);
      *(short8*)&Bs[srow * 40 + shalf + 8] = pb;
      __syncthreads();
      short8 af[4], bfv[4];
#pragma unroll
      for (int i = 0; i < 4; ++i) af[i] = *(short8*)&As[(wm + i * 16 + fr) * 40 + fq * 8];
#pragma unroll
      for (int j = 0; j < 4; ++j) bfv[j] = *(short8*)&Bs[(wn + j * 16 + fr) * 40 + fq * 8];
#pragma unroll
      for (int i = 0; i < 4; ++i)
#pragma unroll
        for (int j = 0; j < 4; ++j)
          acc[i][j] = __builtin_amdgcn_mfma_f32_16x16x32_bf16(af[i], bfv[j], acc[i][j], 0, 0, 0);
    }
#pragma unroll
    for (int j = 0; j < 4; ++j) {
      int col = n0 + wn + j * 16 + fr;
      float bias = (col < G3) ? bf[col] : bb[col - G3];
#pragma unroll
      for (int i = 0; i < 4; ++i) {
        int rowb = m0 + wm + i * 16 + fq * 4;
#pragma unroll
        for (int rg = 0; rg < 4; ++rg)
          C[(size_t)(rowb + rg) * 384 + col] = acc[i][j][rg] + bias;
      }
    }
  } else if (gblk < 896) {
    // ---- qkv projection
    float* Ws = (float*)smem;          // 96*32
    float* bs = Ws + 96 * 32;          // 96
    for (int i = tid; i < 96 * 32; i += 256) Ws[i] = Wqkv[i];
    if (tid < 96) bs[tid] = bqkv[tid];
    __syncthreads();
    const int idx = (gblk - 768) * 256 + tid;
    float x[32];
#pragma unroll
    for (int d4 = 0; d4 < 8; ++d4) {
      float4 v = *(const float4*)&in2[(size_t)idx * 32 + d4 * 4];
      x[d4 * 4 + 0] = v.x; x[d4 * 4 + 1] = v.y; x[d4 * 4 + 2] = v.z; x[d4 * 4 + 3] = v.w;
    }
    float* const dsts[3] = {qb, kb, vb};
#pragma unroll
    for (int p = 0; p < 3; ++p) {
      float a[32];
#pragma unroll
      for (int j = 0; j < 32; ++j) {
        float s = bs[p * 32 + j];
#pragma unroll
        for (int d = 0; d < 32; ++d) s += x[d] * Ws[(p * 32 + j) * 32 + d];
        a[j] = s;
      }
      float* dst = dsts[p];
#pragma unroll
      for (int j4 = 0; j4 < 8; ++j4) {
        float4 o = {a[j4 * 4 + 0], a[j4 * 4 + 1], a[j4 * 4 + 2], a[j4 * 4 + 3]};
        *(float4*)&dst[(size_t)idx * 32 + j4 * 4] = o;
      }
    }
  } else {
    // ---- wcomb
    int e = (gblk - 896) * 256 + tid;
    int i = e >> 4, j = e & 15;
    float a = 0.f;
#pragma unroll
    for (int c = 0; c < 16; ++c) a += Wdense[i * 16 + c] * Wfuse[c * 16 + j];
    wcomb[e] = a;
  }
}

// ================= K_B: gru (0..127) + attn_split (128..639) =================
__global__ __launch_bounds__(256, 1) void mega_b(const float* __restrict__ C,
                                                 const float* __restrict__ Whh_f,
                                                 const float* __restrict__ bhh_f,
                                                 const float* __restrict__ Whh_b,
                                                 const float* __restrict__ bhh_b,
                                                 float* __restrict__ out,
                                                 const float* __restrict__ qb,
                                                 const float* __restrict__ kb,
                                                 const float* __restrict__ vb,
                                                 float* __restrict__ part) {
  __shared__ __align__(16) char smem[33280];
  const int tid = threadIdx.x;
  if (blockIdx.x < 128) {
    // ---- gru (R5 structure, measured 230 µs; 48 wt floats/lane = VGPR-safe)
    float* xs = (float*)smem;            // 32*192
    float* hbuf = xs + 32 * 192;         // 2*64
    float* obuf = hbuf + 128;            // 32*64
    const int wg = blockIdx.x;
    const int rev = (wg >= Bn) ? 1 : 0;
    const int b = wg & (Bn - 1);
    const int w = tid >> 6;
    const int lane = tid & 63;
    const int r = lane >> 2;
    const int kc = lane & 3;
    const int row = 16 * w + r;
    const int k0 = 16 * kc;
    const float* Whh = rev ? Whh_b : Whh_f;
    const float* bhh = rev ? bhh_b : bhh_f;
    const int colBase = rev ? G3 : 0;
    const int dirOff = rev ? Hn : 0;
    float4 wv[3][4];
#pragma unroll
    for (int g = 0; g < 3; ++g)
#pragma unroll
      for (int q = 0; q < 4; ++q) {
        wv[g][q] = *(const float4*)&Whh[(size_t)(g * 64 + row) * 64 + k0 + 4 * q];
        asm volatile("" : "+v"(wv[g][q].x), "+v"(wv[g][q].y), "+v"(wv[g][q].z), "+v"(wv[g][q].w));
      }
    const float brr = bhh[row], bzz = bhh[64 + row], bnn = bhh[128 + row];
    if (tid < 64) { hbuf[tid] = 0.f; hbuf[64 + tid] = 0.f; }
    float h = 0.f;
    for (int c = 0; c < 16; ++c) {
      const int cstart = c * 32;
      if (c > 0) {
#pragma unroll
        for (int i = 0; i < 2; ++i) {
          int f = tid + 256 * i;
          int s = f >> 4;
          int c4 = (f & 15) << 2;
          int tp = cstart - 32 + s;
          int orow = rev ? (Sn - 1 - tp) : tp;
          *(float4*)&out[(size_t)(b * Sn + orow) * 128 + dirOff + c4] = *(const float4*)&obuf[s * 64 + c4];
        }
      }
      float4 st[6];
#pragma unroll
      for (int i = 0; i < 6; ++i) {
        int f = tid + 256 * i;
        int s = f / 48;
        int c4 = (f % 48) << 2;
        int t = cstart + s;
        int grow = rev ? (Sn - 1 - t) : t;
        st[i] = *(const float4*)&C[(size_t)(b * Sn + grow) * 384 + colBase + c4];
      }
#pragma unroll
      for (int i = 0; i < 6; ++i) {
        int f = tid + 256 * i;
        int s = f / 48;
        int c4 = (f % 48) << 2;
        *(float4*)&xs[s * 192 + c4] = st[i];
      }
      __syncthreads();
      float xr = xs[row], xz = xs[64 + row], xn = xs[128 + row];
      for (int s = 0; s < 32; ++s) {
        const int t = cstart + s;
        const int p = t & 1;
        float4 ha = *(const float4*)&hbuf[p * 64 + k0 + 0];
        float4 hb = *(const float4*)&hbuf[p * 64 + k0 + 4];
        float4 hc = *(const float4*)&hbuf[p * 64 + k0 + 8];
        float4 hd = *(const float4*)&hbuf[p * 64 + k0 + 12];
        float nxr = 0.f, nxz = 0.f, nxn = 0.f;
        if (s + 1 < 32) {
          const float* xq = &xs[(s + 1) * 192];
          nxr = xq[row]; nxz = xq[64 + row]; nxn = xq[128 + row];
        }
        float dr, dz, dn;
        {
          float4 wa, wbv, wc, wd;
          wa = wv[0][0]; wbv = wv[0][1]; wc = wv[0][2]; wd = wv[0][3];
          dr = (wa.x * ha.x + wa.y * ha.y + wa.z * ha.z + wa.w * ha.w)
             + (wbv.x * hb.x + wbv.y * hb.y + wbv.z * hb.z + wbv.w * hb.w)
             + (wc.x * hc.x + wc.y * hc.y + wc.z * hc.z + wc.w * hc.w)
             + (wd.x * hd.x + wd.y * hd.y + wd.z * hd.z + wd.w * hd.w);
          wa = wv[1][0]; wbv = wv[1][1]; wc = wv[1][2]; wd = wv[1][3];
          dz = (wa.x * ha.x + wa.y * ha.y + wa.z * ha.z + wa.w * ha.w)
             + (wbv.x * hb.x + wbv.y * hb.y + wbv.z * hb.z + wbv.w * hb.w)
             + (wc.x * hc.x + wc.y * hc.y + wc.z * hc.z + wc.w * hc.w)
             + (wd.x * hd.x + wd.y * hd.y + wd.z * hd.z + wd.w * hd.w);
          wa = wv[2][0]; wbv = wv[2][1]; wc = wv[2][2]; wd = wv[2][3];
          dn = (wa.x * ha.x + wa.y * ha.y + wa.z * ha.z + wa.w * ha.w)
             + (wbv.x * hb.x + wbv.y * hb.y + wbv.z * hb.z + wbv.w * hb.w)
             + (wc.x * hc.x + wc.y * hc.y + wc.z * hc.z + wc.w * hc.w)
             + (wd.x * hd.x + wd.y * hd.y + wd.z * hd.z + wd.w * hd.w);
        }
        dr += __shfl_xor(dr, 1); dr += __shfl_xor(dr, 2);
        dz += __shfl_xor(dz, 1); dz += __shfl_xor(dz, 2);
        dn += __shfl_xor(dn, 1); dn += __shfl_xor(dn, 2);
        float rg = sigmoidf_(xr + brr + dr);
        float zg = sigmoidf_(xz + bzz + dz);
        float ng = tanhf_(xn + rg * (bnn + dn));
        h = (1.f - zg) * ng + zg * h;
        if (kc == 0) {
          hbuf[(p ^ 1) * 64 + row] = h;
          obuf[s * 64 + row] = h;
        }
        __syncthreads();
        xr = nxr; xz = nxz; xn = nxn;
      }
    }
#pragma unroll
    for (int i = 0; i < 2; ++i) {
      int f = tid + 256 * i;
      int s = f >> 4;
      int c4 = (f & 15) << 2;
      int tp = Sn - 32 + s;
      int orow = rev ? (Sn - 1 - tp) : tp;
      *(float4*)&out[(size_t)(b * Sn + orow) * 128 + dirOff + c4] = *(const float4*)&obuf[s * 64 + c4];
    }
  } else {
    // ---- attn_split (flash-style split-K partials)
    float* Ks = (float*)smem;           // 128*32
    float* Vs = Ks + 128 * 32;          // 128*32
    const int blk = blockIdx.x - 128;
    const int b = blk >> 3;
    const int qhalf = (blk >> 2) & 1;
    const int split = blk & 3;
    const int k0 = split * 128;
#pragma unroll
    for (int i = 0; i < 4; ++i) {
      int f = tid + 256 * i;
      int row = f >> 3, col = (f & 7) * 4;
      *(float4*)&Ks[row * 32 + col] = *(const float4*)&kb[(size_t)(b * Sn + k0 + row) * 32 + col];
      *(float4*)&Vs[row * 32 + col] = *(const float4*)&vb[(size_t)(b * Sn + k0 + row) * 32 + col];
    }
    const int q = b * Sn + qhalf * 256 + tid;
    float qv[32];
#pragma unroll
    for (int d4 = 0; d4 < 8; ++d4) {
      float4 v = *(const float4*)&qb[(size_t)q * 32 + d4 * 4];
      qv[d4 * 4 + 0] = v.x; qv[d4 * 4 + 1] = v.y; qv[d4 * 4 + 2] = v.z; qv[d4 * 4 + 3] = v.w;
    }
    __syncthreads();
    const float scale = 0.17677669529663687f;
    float m = -1e30f, lsum = 0.f;
    float acc[32] = {};
    for (int kk = 0; kk < 128; ++kk) {
      const float4* kr = (const float4*)&Ks[kk * 32];
      float s = 0.f;
#pragma unroll
      for (int d4 = 0; d4 < 8; ++d4) {
        float4 kv = kr[d4];
        s += qv[d4 * 4 + 0] * kv.x + qv[d4 * 4 + 1] * kv.y + qv[d4 * 4 + 2] * kv.z + qv[d4 * 4 + 3] * kv.w;
      }
      s *= scale;
      float mn = fmaxf(m, s);
      float e1 = __expf(m - mn);
      float p = __expf(s - mn);
      lsum = lsum * e1 + p;
      const float4* vr = (const float4*)&Vs[kk * 32];
#pragma unroll
      for (int d4 = 0; d4 < 8; ++d4) {
        float4 vv = vr[d4];
        acc[d4 * 4 + 0] = acc[d4 * 4 + 0] * e1 + p * vv.x;
        acc[d4 * 4 + 1] = acc[d4 * 4 + 1] * e1 + p * vv.y;
        acc[d4 * 4 + 2] = acc[d4 * 4 + 2] * e1 + p * vv.z;
        acc[d4 * 4 + 3] = acc[d4 * 4 + 3] * e1 + p * vv.w;
      }
      m = mn;
    }
    float* rec = part + ((size_t)q * 4 + split) * 36;
#pragma unroll
    for (int d4 = 0; d4 < 8; ++d4) {
      float4 o = {acc[d4 * 4 + 0], acc[d4 * 4 + 1], acc[d4 * 4 + 2], acc[d4 * 4 + 3]};
      *(float4*)&rec[d4 * 4] = o;
    }
    rec[32] = m;
    rec[33] = lsum;
  }
}

// ---------------- K_C: combine partials + out_proj ---------------------------
__global__ __launch_bounds__(256) void attn_combine(const float* __restrict__ part,
                                                    const float* __restrict__ Wout,
                                                    const float* __restrict__ bout,
                                                    float* __restrict__ attn) {
  __shared__ float Ws[32 * 32];
  __shared__ float bs[32];
  const int tid = threadIdx.x;
  for (int i = tid; i < 1024; i += 256) Ws[i] = Wout[i];
  if (tid < 32) bs[tid] = bout[tid];
  __syncthreads();
  const int q = blockIdx.x * 256 + tid;
  const float* rec = part + (size_t)q * 4 * 36;
  float m0 = rec[32], m1 = rec[36 + 32], m2 = rec[72 + 32], m3 = rec[108 + 32];
  float M = fmaxf(fmaxf(m0, m1), fmaxf(m2, m3));
  float w0 = __expf(m0 - M), w1 = __expf(m1 - M), w2 = __expf(m2 - M), w3 = __expf(m3 - M);
  float L = rec[33] * w0 + rec[36 + 33] * w1 + rec[72 + 33] * w2 + rec[108 + 33] * w3;
  float inv = 1.f / L;
  float a[32];
#pragma unroll
  for (int d4 = 0; d4 < 8; ++d4) {
    float4 p0 = *(const float4*)&rec[d4 * 4];
    float4 p1 = *(const float4*)&rec[36 + d4 * 4];
    float4 p2 = *(const float4*)&rec[72 + d4 * 4];
    float4 p3 = *(const float4*)&rec[108 + d4 * 4];
    a[d4 * 4 + 0] = (p0.x * w0 + p1.x * w1 + p2.x * w2 + p3.x * w3) * inv;
    a[d4 * 4 + 1] = (p0.y * w0 + p1.y * w1 + p2.y * w2 + p3.y * w3) * inv;
    a[d4 * 4 + 2] = (p0.z * w0 + p1.z * w1 + p2.z * w2 + p3.z * w3) * inv;
    a[d4 * 4 + 3] = (p0.w * w0 + p1.w * w1 + p2.w * w2 + p3.w * w3) * inv;
  }
#pragma unroll
  for (int j = 0; j < 32; ++j) {
    float o = bs[j];
#pragma unroll
    for (int d = 0; d < 32; ++d) o += a[d] * Ws[j * 32 + d];
    attn[(size_t)q * 32 + j] = o;
  }
}

// ---------------- K_D: emissions ---------------------------------------------
__global__ __launch_bounds__(256) void emis_kernel(const float* __restrict__ lstm,
                                                   const float* __restrict__ attn,
                                                   const float* __restrict__ wcomb,
                                                   const float* __restrict__ Wfuse,
                                                   float* __restrict__ emis) {
  __shared__ float Wc[128 * 16];
  __shared__ float Wf2[32 * 16];
  const int tid = threadIdx.x;
  for (int i = tid; i < 2048; i += 256) Wc[i] = wcomb[i];
  for (int i = tid; i < 512; i += 256) Wf2[i] = Wfuse[16 * 16 + i];
  __syncthreads();
  const int idx = blockIdx.x * 256 + tid;
  float acc[16] = {};
  for (int i = 0; i < 128; i += 4) {
    float4 lv = *(const float4*)&lstm[(size_t)idx * 128 + i];
    float ll[4] = {lv.x, lv.y, lv.z, lv.w};
#pragma unroll
    for (int u = 0; u < 4; ++u)
#pragma unroll
      for (int j = 0; j < 16; ++j) acc[j] += ll[u] * Wc[(i + u) * 16 + j];
  }
  for (int d = 0; d < 32; d += 4) {
    float4 av = *(const float4*)&attn[(size_t)idx * 32 + d];
    float aa[4] = {av.x, av.y, av.z, av.w};
#pragma unroll
    for (int u = 0; u < 4; ++u)
#pragma unroll
      for (int j = 0; j < 16; ++j) acc[j] += aa[u] * Wf2[(d + u) * 16 + j];
  }
#pragma unroll
  for (int j = 0; j < 16; j += 4) {
    float4 o = {acc[j], acc[j + 1], acc[j + 2], acc[j + 3]};
    *(float4*)&emis[(size_t)idx * 16 + j] = o;
  }
}

// ================= K_E: numer (0..63) + denom (64..127) ======================
__global__ __launch_bounds__(64) void mega_e(const float* __restrict__ emis,
                                             const int* __restrict__ tgt,
                                             const float* __restrict__ cstart,
                                             const float* __restrict__ cend,
                                             const float* __restrict__ ctrans,
                                             float* __restrict__ numer,
                                             float* __restrict__ denom) {
  if (blockIdx.x < 64) {
    const int b = blockIdx.x, l = threadIdx.x;
    float ssum = 0.f;
    for (int t = l; t < Sn; t += 64) {
      int tg = tgt[b * Sn + t];
      ssum += emis[(size_t)(b * Sn + t) * Tn + tg];
      if (t + 1 < Sn) {
        int tg2 = tgt[b * Sn + t + 1];
        ssum += ctrans[tg * Tn + tg2];
      }
    }
    if (l == 0) ssum += cstart[tgt[b * Sn]] + cend[tgt[b * Sn + Sn - 1]];
    for (int off = 32; off > 0; off >>= 1) ssum += __shfl_down(ssum, off);
    if (l == 0) numer[b] = ssum;
  } else {
    const int b = blockIdx.x - 64;
    const int lane = threadIdx.x;
    const int g = lane >> 4;
    const int j = lane & 15;
    const int i0 = 4 * g;
    float tr0 = ctrans[(i0 + 0) * Tn + j];
    float tr1 = ctrans[(i0 + 1) * Tn + j];
    float tr2 = ctrans[(i0 + 2) * Tn + j];
    float tr3 = ctrans[(i0 + 3) * Tn + j];
    float s = cstart[j] + emis[(size_t)(b * Sn) * Tn + j];
    float em = emis[(size_t)(b * Sn + 1) * Tn + j];
    for (int t = 1; t < Sn; ++t) {
      float s0 = __shfl(s, i0 + 0);
      float s1 = __shfl(s, i0 + 1);
      float s2 = __shfl(s, i0 + 2);
      float s3 = __shfl(s, i0 + 3);
      float v0 = s0 + tr0, v1 = s1 + tr1, v2 = s2 + tr2, v3 = s3 + tr3;
      float m = fmaxf(fmaxf(v0, v1), fmaxf(v2, v3));
      m = fmaxf(m, __shfl_xor(m, 16));
      m = fmaxf(m, __shfl_xor(m, 32));
      float e = __expf(v0 - m) + __expf(v1 - m) + __expf(v2 - m) + __expf(v3 - m);
      e += __shfl_xor(e, 16);
      e += __shfl_xor(e, 32);
      float em_cur = em;
      if (t + 1 < Sn) em = emis[(size_t)(b * Sn + t + 1) * Tn + j];
      s = em_cur + m + __logf(e);
    }
    float f = s + cend[j];
    float m = f;
    m = fmaxf(m, __shfl_xor(m, 1));
    m = fmaxf(m, __shfl_xor(m, 2));
    m = fmaxf(m, __shfl_xor(m, 4));
    m = fmaxf(m, __shfl_xor(m, 8));
    float e = __expf(f - m);
    e += __shfl_xor(e, 1);
    e += __shfl_xor(e, 2);
    e += __shfl_xor(e, 4);
    e += __shfl_xor(e, 8);
    if (lane == 0) denom[b] = m + __logf(e);
  }
}

// ---------------- K_F: final scalar ------------------------------------------
__global__ __launch_bounds__(64) void final_kernel(const float* __restrict__ numer,
                                                   const float* __restrict__ denom,
                                                   float* __restrict__ out) {
  const int l = threadIdx.x;
  float d = denom[l] - numer[l];
  for (int off = 32; off > 0; off >>= 1) d += __shfl_down(d, off);
  if (l == 0) out[0] = d * (1.f / 64.f);
}

extern "C" void kernel_launch(void* const* d_in, const int* in_sizes, int n_in,
                              void* d_out, int out_size, void* d_ws, size_t ws_size,
                              hipStream_t stream) {
  (void)in_sizes; (void)n_in; (void)out_size; (void)ws_size;
  const float* bert = (const float*)d_in[0];
  const float* in2 = (const float*)d_in[1];
  const int* tgt = (const int*)d_in[2];
  const float* Wih_f = (const float*)d_in[3];
  const float* Whh_f = (const float*)d_in[4];
  const float* bih_f = (const float*)d_in[5];
  const float* bhh_f = (const float*)d_in[6];
  const float* Wih_b = (const float*)d_in[7];
  const float* Whh_b = (const float*)d_in[8];
  const float* bih_b = (const float*)d_in[9];
  const float* bhh_b = (const float*)d_in[10];
  const float* Wdense = (const float*)d_in[11];
  const float* in_proj_w = (const float*)d_in[12];
  const float* in_proj_b = (const float*)d_in[13];
  const float* out_proj_w = (const float*)d_in[14];
  const float* out_proj_b = (const float*)d_in[15];
  const float* Wfuse = (const float*)d_in[16];
  const float* cstart = (const float*)d_in[17];
  const float* cend = (const float*)d_in[18];
  const float* ctrans = (const float*)d_in[19];

  float* ws = (float*)d_ws;
  float* C = ws;                                    // B*S*384 (dead after gru -> reused for attn partials)
  float* lstm = C + (size_t)Bn * Sn * 384;          // B*S*128
  float* qb = lstm + (size_t)Bn * Sn * 2 * Hn;      // B*S*32
  float* kb = qb + (size_t)Bn * Sn * Pn;
  float* vb = kb + (size_t)Bn * Sn * Pn;
  float* attn = vb + (size_t)Bn * Sn * Pn;
  float* emis = attn + (size_t)Bn * Sn * Pn;        // B*S*16
  float* wcomb = emis + (size_t)Bn * Sn * Tn;       // 2048
  float* numer = wcomb + 128 * 16;                  // 64
  float* denom = numer + Bn;                        // 64
  // attn partials: must NOT alias C (gru reads C while split writes partials
  // concurrently in mega_b). Place after denom.
  float* part = denom + Bn;                         // 32768*4*36 floats (18.9 MB)

  mega_a<<<904, 256, 0, stream>>>(bert, Wih_f, Wih_b, bih_f, bih_b, C,
                                  in2, in_proj_w, in_proj_b, qb, kb, vb,
                                  Wdense, Wfuse, wcomb);
  mega_b<<<640, 256, 0, stream>>>(C, Whh_f, bhh_f, Whh_b, bhh_b, lstm,
                                  qb, kb, vb, part);
  attn_combine<<<Bn * Sn / 256, 256, 0, stream>>>(part, out_proj_w, out_proj_b, attn);
  emis_kernel<<<Bn * Sn / 256, 256, 0, stream>>>(lstm, attn, wcomb, Wfuse, emis);
  mega_e<<<128, 64, 0, stream>>>(emis, tgt, cstart, cend, ctrans, numer, denom);
  final_kernel<<<1, 64, 0, stream>>>(numer, denom, (float*)d_out);
}